// Round 12
// baseline (41.607 us; speedup 1.0000x reference)
//
#include <hip/hip_runtime.h>
#include <hip/hip_bf16.h>

typedef __attribute__((ext_vector_type(8))) short s16x8;
typedef __attribute__((ext_vector_type(4))) short s16x4;
typedef __attribute__((ext_vector_type(4))) float fx4;

#define DEVINL __device__ __forceinline__

constexpr int EMBED = 768;
constexpr int HD    = 64;
constexpr int NB    = 16;
constexpr int LEN   = 1024;
constexpr int M_TOT = NB * LEN;   // 16384
constexpr int KVQ   = LEN / 4;    // 256 kv per group in fused attn
constexpr int WELEM = HD * EMBED; // 49152
constexpr int NSTEP = EMBED / 32; // 24

// fp32 -> bf16 RNE via v_cvt_pk_bf16_f32 (2 elems/inst).
DEVINL unsigned pk2(float lo, float hi) {
  __hip_bfloat162 h = __float22bfloat162_rn(float2{lo, hi});
  union { __hip_bfloat162 h; unsigned u; } c; c.h = h;
  return c.u;
}
DEVINL s16x8 cvt8(fx4 a, fx4 b) {
  union { unsigned u[4]; s16x8 v; } r;
  r.u[0] = pk2(a[0], a[1]); r.u[1] = pk2(a[2], a[3]);
  r.u[2] = pk2(b[0], b[1]); r.u[3] = pk2(b[2], b[3]);
  return r.v;
}
DEVINL s16x4 cvt4(float a0, float a1, float a2, float a3) {
  union { unsigned u[2]; s16x4 v; } r;
  r.u[0] = pk2(a0, a1); r.u[1] = pk2(a2, a3);
  return r.v;
}

DEVINL fx4 mfma16(s16x8 a, s16x8 b, fx4 c) {
  return __builtin_amdgcn_mfma_f32_16x16x32_bf16(a, b, c, 0, 0, 0);
}

// async global->LDS DMA, 16B/lane; LDS dest = wave-uniform base + lane*16,
// global source = per-lane (enables source-side swizzle, m173 pattern).
DEVINL void gload16(const void* g, void* l) {
  __builtin_amdgcn_global_load_lds(
      (const __attribute__((address_space(1))) void*)g,
      (__attribute__((address_space(3))) void*)l, 16, 0, 0);
}

// ---------------------------------------------------------------------------
// One-shot: convert Wq|Wk|Wv (each 64x768 fp32) to bf16, packed [3][49152].
// ---------------------------------------------------------------------------
__global__ __launch_bounds__(256) void convert_w_kernel(
    const float* __restrict__ a, const float* __restrict__ b,
    const float* __restrict__ c, short* __restrict__ out)
{
  const int gid = blockIdx.x * 256 + threadIdx.x;   // 18432 threads, 8 elem each
  const int seg = gid / (WELEM / 8);
  const int off = (gid % (WELEM / 8)) * 8;
  const float* src = (seg == 0) ? a : (seg == 1) ? b : c;
  fx4 v0 = *reinterpret_cast<const fx4*>(src + off);
  fx4 v1 = *reinterpret_cast<const fx4*>(src + off + 4);
  *reinterpret_cast<s16x8*>(out + (size_t)seg * WELEM + off) = cvt8(v0, v1);
}

// ---------------------------------------------------------------------------
// Round-12 projection: r11's m97-style step-loop, residency 2 -> 4 blocks/CU.
// 1024 blocks x 256 thr: [0,512) Q from dec, [512,1024) K+V^T from enc.
// BM=32 rows/block, 24 K-steps of BK=32, double-buffered 12KB buffers
// (24KB LDS/block -> 4 blocks/CU; their barrier drains interleave, which is
// what sets the staging duty cycle in this structure).
// Per step per wave: 1 X gload16 + 1 W1 gload16 (+1 W2 for KV).
// Wave = n-quadrant w; per step 2 (Q) / 4 (KV) MFMA over m-halves.
// Source-XOR swizzles: X (row&7)<<4 -> ~2-way on read; W (row&3)<<4.
// ---------------------------------------------------------------------------
__global__ __launch_bounds__(256, 4) void proj_kernel(
    const float* __restrict__ dec, const float* __restrict__ enc,
    const short* __restrict__ wbuf,   // [3][WELEM] bf16: Wq | Wk | Wv
    const float* __restrict__ bq, const float* __restrict__ bk,
    const float* __restrict__ bv,
    short* __restrict__ Qout, short* __restrict__ Kout,
    short* __restrict__ VT)
{
  // buffer b at smem + b*12288: X [32][128B] @0, W1 [64][64B] @4096,
  // W2 [64][64B] @8192 (KV only)
  __shared__ __align__(16) char smem[24576];

  const int t = threadIdx.x, lane = t & 63, w = t >> 6;
  const int fr = lane & 15, fg = lane >> 4;
  const bool isQ = blockIdx.x < 512u;
  const int bx = isQ ? blockIdx.x : blockIdx.x - 512;
  const int m0 = bx * 32;
  const float* X = isQ ? dec : enc;
  const char* Xg  = (const char*)(X + (size_t)m0 * EMBED);
  const char* W1g = (const char*)(isQ ? wbuf : wbuf + WELEM);
  const char* W2g = (const char*)(wbuf + 2 * (size_t)WELEM);

  // per-lane source addresses (constant over steps)
  const int xp   = w * 1024 + lane * 16;   // byte pos in 4KB X tile
  const int xrow = xp >> 7, xcol = xp & 127;
  const int xsrc = xrow * 3072 + (xcol ^ ((xrow & 7) << 4));
  const int wrow = w * 16 + (lane >> 2), wcol = (lane & 3) * 16;
  const int wsrc = wrow * 1536 + (wcol ^ ((wrow & 3) << 4));

  fx4 acc1[2], acc2[2];
#pragma unroll
  for (int j = 0; j < 2; ++j) {
    acc1[j] = fx4{0.f, 0.f, 0.f, 0.f};
    acc2[j] = fx4{0.f, 0.f, 0.f, 0.f};
  }

  // fragment-read constants (wave w owns n-quadrant w)
  const int xsw = (fr & 7) << 4;           // (mh*16+fr)&7 == fr&7
  const int wo  = (w * 16 + fr) * 64 + ((fg * 16) ^ ((fr & 3) << 4));

  // prologue: stage step 0
  gload16(Xg + xsrc, smem + w * 1024);
  gload16(W1g + wsrc, smem + 4096 + w * 1024);
  if (!isQ) gload16(W2g + wsrc, smem + 8192 + w * 1024);
  __syncthreads();

#pragma unroll 2
  for (int k = 0; k < NSTEP; ++k) {
    char* cur = smem + (k & 1) * 12288;
    if (k + 1 < NSTEP) {
      char* nxt = smem + ((k + 1) & 1) * 12288;
      gload16(Xg + (k + 1) * 128 + xsrc, nxt + w * 1024);
      gload16(W1g + (k + 1) * 64 + wsrc, nxt + 4096 + w * 1024);
      if (!isQ) gload16(W2g + (k + 1) * 64 + wsrc, nxt + 8192 + w * 1024);
    }
    // compute current step
    s16x8 xa[2];
#pragma unroll
    for (int mh = 0; mh < 2; ++mh) {
      const char* xrb = cur + (mh * 16 + fr) * 128;
      fx4 xlo = *reinterpret_cast<const fx4*>(xrb + ((fg * 32) ^ xsw));
      fx4 xhi = *reinterpret_cast<const fx4*>(xrb + ((fg * 32 + 16) ^ xsw));
      xa[mh] = cvt8(xlo, xhi);
    }
    s16x8 wf1 = *reinterpret_cast<const s16x8*>(cur + 4096 + wo);
    acc1[0] = mfma16(wf1, xa[0], acc1[0]);
    acc1[1] = mfma16(wf1, xa[1], acc1[1]);
    if (!isQ) {
      s16x8 wf2 = *reinterpret_cast<const s16x8*>(cur + 8192 + wo);
      acc2[0] = mfma16(wf2, xa[0], acc2[0]);
      acc2[1] = mfma16(wf2, xa[1], acc2[1]);
    }
    __syncthreads();
  }

  // epilogue: D[n][m]: n = w*16+fg*4+r, m-col = fr; m = m0 + mh*16 + fr
  const int n0 = w * 16 + fg * 4;
  if (isQ) {
    fx4 bb = *reinterpret_cast<const fx4*>(bq + n0);
#pragma unroll
    for (int mh = 0; mh < 2; ++mh)
      *reinterpret_cast<s16x4*>(Qout + (size_t)(m0 + mh * 16 + fr) * HD + n0) =
          cvt4(acc1[mh][0] + bb[0], acc1[mh][1] + bb[1],
               acc1[mh][2] + bb[2], acc1[mh][3] + bb[3]);
  } else {
    fx4 bb = *reinterpret_cast<const fx4*>(bk + n0);
#pragma unroll
    for (int mh = 0; mh < 2; ++mh)
      *reinterpret_cast<s16x4*>(Kout + (size_t)(m0 + mh * 16 + fr) * HD + n0) =
          cvt4(acc1[mh][0] + bb[0], acc1[mh][1] + bb[1],
               acc1[mh][2] + bb[2], acc1[mh][3] + bb[3]);
    fx4 vb = *reinterpret_cast<const fx4*>(bv + n0);
    const int bidx = m0 >> 10;               // 32 | 1024: no batch straddle
#pragma unroll
    for (int mh = 0; mh < 2; ++mh) {
      const int kvp = (m0 & 1023) + mh * 16 + fr;
#pragma unroll
      for (int r = 0; r < 4; ++r)
        VT[((size_t)(bidx * HD + n0 + r)) * LEN + kvp] =
            (short)pk2(acc2[mh][r] + vb[r], 0.f);
    }
  }
}

// ---------------------------------------------------------------------------
// Fused flash attention (unchanged; ~3.5 us). 1024 threads = 16 waves =
// 4 KV-groups x 4 q-waves; K/V LDS-staged per group; lane-local softmax;
// partial combine through LDS overlay.
// ---------------------------------------------------------------------------
__global__ __launch_bounds__(1024, 4) void attn_kernel(
    const short* __restrict__ Q, const short* __restrict__ K,
    const short* __restrict__ VT, float* __restrict__ Out)
{
  __shared__ __align__(16) char smem[110592];
  short (*Kls)[64][72]  = reinterpret_cast<short(*)[64][72]>(smem);
  short (*Vls)[64][72]  = reinterpret_cast<short(*)[64][72]>(smem + 36864);
  short (*Plds)[16][72] = reinterpret_cast<short(*)[16][72]>(smem + 73728);
  float (*HL)[64][68]   = reinterpret_cast<float(*)[64][68]>(smem);
  float2 (*ML)[64]      = reinterpret_cast<float2(*)[64]>(smem + 69632);

  const int t = threadIdx.x, lane = t & 63, w = t >> 6;
  const int g = w >> 2, wl = w & 3;
  const int fr = lane & 15, fg = lane >> 4;
  const int xcd = blockIdx.x & 7;
  const int idx = blockIdx.x >> 3;        // 0..31
  const int b   = xcd + ((idx & 1) << 3);
  const int q0  = (idx >> 1) * 64;
  const int qrow = q0 + wl * 16;

  const short* Qb  = Q  + (size_t)b * LEN * HD;
  const short* Kb  = K  + ((size_t)b * LEN + g * KVQ) * HD;
  const short* VTb = VT + (size_t)b * HD * LEN + g * KVQ;

  s16x8 qa0 = *reinterpret_cast<const s16x8*>(Qb + (size_t)(qrow + fr) * HD + fg * 8);
  s16x8 qa1 = *reinterpret_cast<const s16x8*>(Qb + (size_t)(qrow + fr) * HD + 32 + fg * 8);

  fx4 hacc[4];
#pragma unroll
  for (int c = 0; c < 4; ++c) hacc[c] = fx4{0.f, 0.f, 0.f, 0.f};
  float mrun = -1e30f, lsum = 0.f;
  const float SC = 0.125f * 1.44269504088896340736f;  // 1/sqrt(64) * log2(e)

  const int u = t & 255;
  const int srow = u >> 2;          // 0..63
  const int sch  = (u & 3) * 16;    // short col offset: 0,16,32,48 (32B/lane)

  s16x8 pk0 = *reinterpret_cast<const s16x8*>(Kb + (size_t)srow * HD + sch);
  s16x8 pk1 = *reinterpret_cast<const s16x8*>(Kb + (size_t)srow * HD + sch + 8);
  s16x8 pv0 = *reinterpret_cast<const s16x8*>(VTb + (size_t)srow * LEN + sch);
  s16x8 pv1 = *reinterpret_cast<const s16x8*>(VTb + (size_t)srow * LEN + sch + 8);
  *reinterpret_cast<s16x8*>(&Kls[g][srow][sch])     = pk0;
  *reinterpret_cast<s16x8*>(&Kls[g][srow][sch + 8]) = pk1;
  *reinterpret_cast<s16x8*>(&Vls[g][srow][sch])     = pv0;
  *reinterpret_cast<s16x8*>(&Vls[g][srow][sch + 8]) = pv1;
  __syncthreads();

#pragma unroll
  for (int it = 0; it < KVQ / 64; ++it) {
    if (it + 1 < KVQ / 64) {  // issue next tile's loads before compute
      const int nk = (it + 1) * 64;
      pk0 = *reinterpret_cast<const s16x8*>(Kb + (size_t)(nk + srow) * HD + sch);
      pk1 = *reinterpret_cast<const s16x8*>(Kb + (size_t)(nk + srow) * HD + sch + 8);
      pv0 = *reinterpret_cast<const s16x8*>(VTb + (size_t)srow * LEN + nk + sch);
      pv1 = *reinterpret_cast<const s16x8*>(VTb + (size_t)srow * LEN + nk + sch + 8);
    }
    fx4 sacc[4];
#pragma unroll
    for (int s = 0; s < 4; ++s) {
      s16x8 kf0 = *reinterpret_cast<const s16x8*>(&Kls[g][s * 16 + fr][fg * 8]);
      s16x8 kf1 = *reinterpret_cast<const s16x8*>(&Kls[g][s * 16 + fr][32 + fg * 8]);
      fx4 z = fx4{0.f, 0.f, 0.f, 0.f};
      z = mfma16(kf0, qa0, z);
      sacc[s] = mfma16(kf1, qa1, z);
    }
    float xs[4][4];
    float xm = -1e30f;
#pragma unroll
    for (int s = 0; s < 4; ++s)
#pragma unroll
      for (int r = 0; r < 4; ++r) {
        xs[s][r] = sacc[s][r] * SC;
        xm = fmaxf(xm, xs[s][r]);
      }
    xm = fmaxf(xm, __shfl_xor(xm, 16, 64));
    xm = fmaxf(xm, __shfl_xor(xm, 32, 64));
    const float mn = fmaxf(mrun, xm);
    const float corr = __builtin_amdgcn_exp2f(mrun - mn);
    mrun = mn;
    float ps = 0.f;
#pragma unroll
    for (int s = 0; s < 4; ++s) {
      float p[4];
#pragma unroll
      for (int r = 0; r < 4; ++r) {
        p[r] = __builtin_amdgcn_exp2f(xs[s][r] - mn);
        ps += p[r];
      }
      *reinterpret_cast<s16x4*>(&Plds[w][fr][s * 16 + fg * 4]) =
          cvt4(p[0], p[1], p[2], p[3]);
    }
    ps += __shfl_xor(ps, 16, 64);
    ps += __shfl_xor(ps, 32, 64);
    lsum = lsum * corr + ps;
    __builtin_amdgcn_wave_barrier();
    s16x8 pa0 = *reinterpret_cast<const s16x8*>(&Plds[w][fr][fg * 8]);
    s16x8 pa1 = *reinterpret_cast<const s16x8*>(&Plds[w][fr][32 + fg * 8]);
#pragma unroll
    for (int c = 0; c < 4; ++c) {
      s16x8 vf0 = *reinterpret_cast<const s16x8*>(&Vls[g][c * 16 + fr][fg * 8]);
      s16x8 vf1 = *reinterpret_cast<const s16x8*>(&Vls[g][c * 16 + fr][32 + fg * 8]);
      fx4 h = hacc[c];
#pragma unroll
      for (int r = 0; r < 4; ++r) h[r] *= corr;
      h = mfma16(vf0, pa0, h);
      hacc[c] = mfma16(vf1, pa1, h);
    }
    __syncthreads();  // all waves done reading tile it
    if (it + 1 < KVQ / 64) {
      *reinterpret_cast<s16x8*>(&Kls[g][srow][sch])     = pk0;
      *reinterpret_cast<s16x8*>(&Kls[g][srow][sch + 8]) = pk1;
      *reinterpret_cast<s16x8*>(&Vls[g][srow][sch])     = pv0;
      *reinterpret_cast<s16x8*>(&Vls[g][srow][sch + 8]) = pv1;
    }
    __syncthreads();  // tile it+1 visible
  }
#pragma unroll
  for (int c = 0; c < 4; ++c)
    *reinterpret_cast<fx4*>(&HL[g][wl * 16 + fr][c * 16 + fg * 4]) = hacc[c];
  if (fg == 0) ML[g][wl * 16 + fr] = make_float2(mrun, lsum);
  __syncthreads();
  const int row = t >> 4, d0 = (t & 15) * 4;
  const float2 s0 = ML[0][row], s1 = ML[1][row], s2 = ML[2][row], s3 = ML[3][row];
  const float mm = fmaxf(fmaxf(s0.x, s1.x), fmaxf(s2.x, s3.x));
  const float w0 = __builtin_amdgcn_exp2f(s0.x - mm);
  const float w1 = __builtin_amdgcn_exp2f(s1.x - mm);
  const float w2 = __builtin_amdgcn_exp2f(s2.x - mm);
  const float w3 = __builtin_amdgcn_exp2f(s3.x - mm);
  const float inv = 1.0f / (s0.y * w0 + s1.y * w1 + s2.y * w2 + s3.y * w3);
  fx4 h0 = *reinterpret_cast<const fx4*>(&HL[0][row][d0]);
  fx4 h1 = *reinterpret_cast<const fx4*>(&HL[1][row][d0]);
  fx4 h2 = *reinterpret_cast<const fx4*>(&HL[2][row][d0]);
  fx4 h3 = *reinterpret_cast<const fx4*>(&HL[3][row][d0]);
  fx4 o;
#pragma unroll
  for (int r = 0; r < 4; ++r)
    o[r] = (h0[r] * w0 + h1[r] * w1 + h2[r] * w2 + h3[r] * w3) * inv;
  *reinterpret_cast<fx4*>(Out + ((size_t)b * LEN + q0 + row) * HD + d0) = o;
}

extern "C" void kernel_launch(void* const* d_in, const int* in_sizes, int n_in,
                              void* d_out, int out_size, void* d_ws, size_t ws_size,
                              hipStream_t stream) {
  const float* dec = (const float*)d_in[0];
  const float* enc = (const float*)d_in[1];
  const float* Wq  = (const float*)d_in[2];
  const float* bq  = (const float*)d_in[3];
  const float* Wk  = (const float*)d_in[4];
  const float* bk  = (const float*)d_in[5];
  const float* Wv  = (const float*)d_in[6];
  const float* bv  = (const float*)d_in[7];
  float* out = (float*)d_out;

  short* qws  = (short*)d_ws;                        // [16384,64] bf16
  short* kws  = qws + (size_t)M_TOT * HD;            // [16384,64] bf16
  short* vtws = kws + (size_t)M_TOT * HD;            // [16,64,1024] bf16
  short* wbuf = vtws + (size_t)NB * HD * LEN;        // [3][49152] bf16 weights

  convert_w_kernel<<<(3 * WELEM / 8) / 256, 256, 0, stream>>>(Wq, Wk, Wv, wbuf);
  proj_kernel<<<1024, 256, 0, stream>>>(
      dec, enc, wbuf, bq, bk, bv, qws, kws, vtws);
  attn_kernel<<<NB * (LEN / 64), 1024, 0, stream>>>(qws, kws, vtws, out);
}

// Round 13
// 40.402 us; speedup vs baseline: 1.0298x; 1.0298x over previous
//
#include <hip/hip_runtime.h>
#include <hip/hip_bf16.h>

typedef __attribute__((ext_vector_type(8))) short s16x8;
typedef __attribute__((ext_vector_type(4))) short s16x4;
typedef __attribute__((ext_vector_type(4))) float fx4;

#define DEVINL __device__ __forceinline__

constexpr int EMBED = 768;
constexpr int HD    = 64;
constexpr int NB    = 16;
constexpr int LEN   = 1024;
constexpr int M_TOT = NB * LEN;   // 16384
constexpr int KVQ   = LEN / 4;    // 256 kv per group in fused attn
constexpr int WELEM = HD * EMBED; // 49152
constexpr int NSTEP = EMBED / 32; // 24

// fp32 -> bf16 RNE via v_cvt_pk_bf16_f32 (2 elems/inst).
DEVINL unsigned pk2(float lo, float hi) {
  __hip_bfloat162 h = __float22bfloat162_rn(float2{lo, hi});
  union { __hip_bfloat162 h; unsigned u; } c; c.h = h;
  return c.u;
}
DEVINL s16x8 cvt8(fx4 a, fx4 b) {
  union { unsigned u[4]; s16x8 v; } r;
  r.u[0] = pk2(a[0], a[1]); r.u[1] = pk2(a[2], a[3]);
  r.u[2] = pk2(b[0], b[1]); r.u[3] = pk2(b[2], b[3]);
  return r.v;
}
DEVINL s16x4 cvt4(float a0, float a1, float a2, float a3) {
  union { unsigned u[2]; s16x4 v; } r;
  r.u[0] = pk2(a0, a1); r.u[1] = pk2(a2, a3);
  return r.v;
}

DEVINL fx4 mfma16(s16x8 a, s16x8 b, fx4 c) {
  return __builtin_amdgcn_mfma_f32_16x16x32_bf16(a, b, c, 0, 0, 0);
}

// async global->LDS DMA, 16B/lane; LDS dest = wave-uniform base + lane*16,
// global source = per-lane (enables source-side swizzle, m173 pattern).
DEVINL void gload16(const void* g, void* l) {
  __builtin_amdgcn_global_load_lds(
      (const __attribute__((address_space(1))) void*)g,
      (__attribute__((address_space(3))) void*)l, 16, 0, 0);
}

// ---------------------------------------------------------------------------
// One-shot: convert Wq|Wk|Wv (each 64x768 fp32) to bf16, packed [3][49152].
// ---------------------------------------------------------------------------
__global__ __launch_bounds__(256) void convert_w_kernel(
    const float* __restrict__ a, const float* __restrict__ b,
    const float* __restrict__ c, short* __restrict__ out)
{
  const int gid = blockIdx.x * 256 + threadIdx.x;   // 18432 threads, 8 elem each
  const int seg = gid / (WELEM / 8);
  const int off = (gid % (WELEM / 8)) * 8;
  const float* src = (seg == 0) ? a : (seg == 1) ? b : c;
  fx4 v0 = *reinterpret_cast<const fx4*>(src + off);
  fx4 v1 = *reinterpret_cast<const fx4*>(src + off + 4);
  *reinterpret_cast<s16x8*>(out + (size_t)seg * WELEM + off) = cvt8(v0, v1);
}

// ---------------------------------------------------------------------------
// Round-13 projection: counted-vmcnt pipeline (T4). The r6-r12 invariant
// (warm == cold ~41us) proved the per-step __syncthreads vmcnt(0) drain was
// the bottleneck: every step paid full memory latency serially. Here:
//   prologue: stage(0); stage(1)
//   loop k:  s_waitcnt vmcnt(NL)  <- S(k) done, S(k+1) STAYS IN FLIGHT
//            s_barrier (raw, no drain)
//            compute buf[k&1]
//            s_barrier (reads done)
//            stage(k+2) -> buf[k&1]   (lands during step k+1's compute)
//   last step peeled with vmcnt(0).
// BM=128, grid 256 (128 Q + 128 KV) -> every CU busy, W traffic amortized
// (staged bytes 240 -> 132 MB). Wave = m-quarter (32 rows), full N=64.
// LDS 48KB = 2 x (X 16KB fp32 + W 8KB bf16), source-XOR swizzles as r11/r12.
// NL: Q = 5 DMA/wave/step (4 X + 1 W), KV = 6 (4 X + 2 W) -> template.
// ---------------------------------------------------------------------------
template <bool ISQ>
DEVINL void proj_body(const float* __restrict__ X,
                      const short* __restrict__ W1g, const short* __restrict__ W2g,
                      const float* __restrict__ b1, const float* __restrict__ b2,
                      short* __restrict__ O1, short* __restrict__ VT,
                      int m0, char* smem)
{
  constexpr int BUFSZ = 24576;  // X 16384 + W1 4096 + W2 4096
  const int t = threadIdx.x, lane = t & 63, w = t >> 6;
  const int fr = lane & 15, fg = lane >> 4;

  const char* Xg = (const char*)(X + (size_t)m0 * EMBED);

  // staging source addresses (constant over steps)
  int xsrc[4];
#pragma unroll
  for (int j = 0; j < 4; ++j) {
    const int xp = w * 4096 + j * 1024 + lane * 16;
    const int row = xp >> 7, col = xp & 127;
    xsrc[j] = row * 3072 + (col ^ ((row & 7) << 4));
  }
  const int wp = w * 1024 + lane * 16;
  const int wrow = wp >> 6, wcol = wp & 63;
  const int wsrc = wrow * 1536 + (wcol ^ ((wrow & 3) << 4));

  auto stage = [&](int k) {
    char* buf = smem + (k & 1) * BUFSZ;
    const int xo = k * 128, wo = k * 64;
#pragma unroll
    for (int j = 0; j < 4; ++j)
      gload16(Xg + xo + xsrc[j], buf + w * 4096 + j * 1024);
    gload16((const char*)W1g + wo + wsrc, buf + 16384 + w * 1024);
    if (!ISQ)
      gload16((const char*)W2g + wo + wsrc, buf + 20480 + w * 1024);
  };

  fx4 acc1[2][4], acc2[2][4];
#pragma unroll
  for (int i = 0; i < 2; ++i)
#pragma unroll
    for (int j = 0; j < 4; ++j) {
      acc1[i][j] = fx4{0.f, 0.f, 0.f, 0.f};
      acc2[i][j] = fx4{0.f, 0.f, 0.f, 0.f};
    }

  stage(0);
  stage(1);

  const int xsw = (fr & 7) << 4;   // (w*32+msub*16+fr)&7 == fr&7
  const int mrow0 = w * 32 + fr;

  auto compute = [&](int k) {
    const char* cur = smem + (k & 1) * BUFSZ;
    s16x8 xa[2];
#pragma unroll
    for (int ms = 0; ms < 2; ++ms) {
      const char* xrb = cur + (mrow0 + ms * 16) * 128;
      fx4 xlo = *reinterpret_cast<const fx4*>(xrb + ((fg * 32) ^ xsw));
      fx4 xhi = *reinterpret_cast<const fx4*>(xrb + ((fg * 32 + 16) ^ xsw));
      xa[ms] = cvt8(xlo, xhi);
    }
#pragma unroll
    for (int ns = 0; ns < 4; ++ns) {
      const int wr = ns * 16 + fr;
      const int wo = wr * 64 + ((fg * 16) ^ ((wr & 3) << 4));
      s16x8 wf1 = *reinterpret_cast<const s16x8*>(cur + 16384 + wo);
      acc1[0][ns] = mfma16(wf1, xa[0], acc1[0][ns]);
      acc1[1][ns] = mfma16(wf1, xa[1], acc1[1][ns]);
      if (!ISQ) {
        s16x8 wf2 = *reinterpret_cast<const s16x8*>(cur + 20480 + wo);
        acc2[0][ns] = mfma16(wf2, xa[0], acc2[0][ns]);
        acc2[1][ns] = mfma16(wf2, xa[1], acc2[1][ns]);
      }
    }
  };

  for (int k = 0; k < NSTEP - 1; ++k) {
    // S(k) complete; S(k+1) (NL instrs) stays in flight across the barrier
    if (ISQ) asm volatile("s_waitcnt vmcnt(5)" ::: "memory");
    else     asm volatile("s_waitcnt vmcnt(6)" ::: "memory");
    __builtin_amdgcn_s_barrier();
    compute(k);
    __builtin_amdgcn_s_barrier();       // all waves done reading buf[k&1]
    if (k + 2 < NSTEP) stage(k + 2);    // overwrite buf[k&1]; lands next step
  }
  // peeled final step: drain everything
  asm volatile("s_waitcnt vmcnt(0)" ::: "memory");
  __builtin_amdgcn_s_barrier();
  compute(NSTEP - 1);

  // epilogue: D[n][m]: n = ns*16+fg*4+r, m-col = fr; m = m0+w*32+ms*16+fr
#pragma unroll
  for (int ms = 0; ms < 2; ++ms) {
    const int m = m0 + w * 32 + ms * 16 + fr;
#pragma unroll
    for (int ns = 0; ns < 4; ++ns) {
      const int n0 = ns * 16 + fg * 4;
      fx4 bb = *reinterpret_cast<const fx4*>(b1 + n0);
      *reinterpret_cast<s16x4*>(O1 + (size_t)m * HD + n0) =
          cvt4(acc1[ms][ns][0] + bb[0], acc1[ms][ns][1] + bb[1],
               acc1[ms][ns][2] + bb[2], acc1[ms][ns][3] + bb[3]);
      if (!ISQ) {
        fx4 vb = *reinterpret_cast<const fx4*>(b2 + n0);
        const int bidx = m0 >> 10;            // 128 | 1024: no straddle
        const int kvp = (m0 & 1023) + w * 32 + ms * 16 + fr;
#pragma unroll
        for (int r = 0; r < 4; ++r)
          VT[((size_t)(bidx * HD + n0 + r)) * LEN + kvp] =
              (short)pk2(acc2[ms][ns][r] + vb[r], 0.f);
      }
    }
  }
}

__global__ __launch_bounds__(256, 2) void proj_kernel(
    const float* __restrict__ dec, const float* __restrict__ enc,
    const short* __restrict__ wbuf,   // [3][WELEM] bf16: Wq | Wk | Wv
    const float* __restrict__ bq, const float* __restrict__ bk,
    const float* __restrict__ bv,
    short* __restrict__ Qout, short* __restrict__ Kout,
    short* __restrict__ VT)
{
  __shared__ __align__(16) char smem[49152];
  if (blockIdx.x < 128) {
    proj_body<true>(dec, wbuf, nullptr, bq, nullptr,
                    Qout, nullptr, (int)blockIdx.x * 128, smem);
  } else {
    proj_body<false>(enc, wbuf + WELEM, wbuf + 2 * (size_t)WELEM, bk, bv,
                     Kout, VT, ((int)blockIdx.x - 128) * 128, smem);
  }
}

// ---------------------------------------------------------------------------
// Fused flash attention (unchanged; ~3.5 us). 1024 threads = 16 waves =
// 4 KV-groups x 4 q-waves; K/V LDS-staged per group; lane-local softmax;
// partial combine through LDS overlay.
// ---------------------------------------------------------------------------
__global__ __launch_bounds__(1024, 4) void attn_kernel(
    const short* __restrict__ Q, const short* __restrict__ K,
    const short* __restrict__ VT, float* __restrict__ Out)
{
  __shared__ __align__(16) char smem[110592];
  short (*Kls)[64][72]  = reinterpret_cast<short(*)[64][72]>(smem);
  short (*Vls)[64][72]  = reinterpret_cast<short(*)[64][72]>(smem + 36864);
  short (*Plds)[16][72] = reinterpret_cast<short(*)[16][72]>(smem + 73728);
  float (*HL)[64][68]   = reinterpret_cast<float(*)[64][68]>(smem);
  float2 (*ML)[64]      = reinterpret_cast<float2(*)[64]>(smem + 69632);

  const int t = threadIdx.x, lane = t & 63, w = t >> 6;
  const int g = w >> 2, wl = w & 3;
  const int fr = lane & 15, fg = lane >> 4;
  const int xcd = blockIdx.x & 7;
  const int idx = blockIdx.x >> 3;        // 0..31
  const int b   = xcd + ((idx & 1) << 3);
  const int q0  = (idx >> 1) * 64;
  const int qrow = q0 + wl * 16;

  const short* Qb  = Q  + (size_t)b * LEN * HD;
  const short* Kb  = K  + ((size_t)b * LEN + g * KVQ) * HD;
  const short* VTb = VT + (size_t)b * HD * LEN + g * KVQ;

  s16x8 qa0 = *reinterpret_cast<const s16x8*>(Qb + (size_t)(qrow + fr) * HD + fg * 8);
  s16x8 qa1 = *reinterpret_cast<const s16x8*>(Qb + (size_t)(qrow + fr) * HD + 32 + fg * 8);

  fx4 hacc[4];
#pragma unroll
  for (int c = 0; c < 4; ++c) hacc[c] = fx4{0.f, 0.f, 0.f, 0.f};
  float mrun = -1e30f, lsum = 0.f;
  const float SC = 0.125f * 1.44269504088896340736f;  // 1/sqrt(64) * log2(e)

  const int u = t & 255;
  const int srow = u >> 2;          // 0..63
  const int sch  = (u & 3) * 16;    // short col offset: 0,16,32,48 (32B/lane)

  s16x8 pk0 = *reinterpret_cast<const s16x8*>(Kb + (size_t)srow * HD + sch);
  s16x8 pk1 = *reinterpret_cast<const s16x8*>(Kb + (size_t)srow * HD + sch + 8);
  s16x8 pv0 = *reinterpret_cast<const s16x8*>(VTb + (size_t)srow * LEN + sch);
  s16x8 pv1 = *reinterpret_cast<const s16x8*>(VTb + (size_t)srow * LEN + sch + 8);
  *reinterpret_cast<s16x8*>(&Kls[g][srow][sch])     = pk0;
  *reinterpret_cast<s16x8*>(&Kls[g][srow][sch + 8]) = pk1;
  *reinterpret_cast<s16x8*>(&Vls[g][srow][sch])     = pv0;
  *reinterpret_cast<s16x8*>(&Vls[g][srow][sch + 8]) = pv1;
  __syncthreads();

#pragma unroll
  for (int it = 0; it < KVQ / 64; ++it) {
    if (it + 1 < KVQ / 64) {  // issue next tile's loads before compute
      const int nk = (it + 1) * 64;
      pk0 = *reinterpret_cast<const s16x8*>(Kb + (size_t)(nk + srow) * HD + sch);
      pk1 = *reinterpret_cast<const s16x8*>(Kb + (size_t)(nk + srow) * HD + sch + 8);
      pv0 = *reinterpret_cast<const s16x8*>(VTb + (size_t)srow * LEN + nk + sch);
      pv1 = *reinterpret_cast<const s16x8*>(VTb + (size_t)srow * LEN + nk + sch + 8);
    }
    fx4 sacc[4];
#pragma unroll
    for (int s = 0; s < 4; ++s) {
      s16x8 kf0 = *reinterpret_cast<const s16x8*>(&Kls[g][s * 16 + fr][fg * 8]);
      s16x8 kf1 = *reinterpret_cast<const s16x8*>(&Kls[g][s * 16 + fr][32 + fg * 8]);
      fx4 z = fx4{0.f, 0.f, 0.f, 0.f};
      z = mfma16(kf0, qa0, z);
      sacc[s] = mfma16(kf1, qa1, z);
    }
    float xs[4][4];
    float xm = -1e30f;
#pragma unroll
    for (int s = 0; s < 4; ++s)
#pragma unroll
      for (int r = 0; r < 4; ++r) {
        xs[s][r] = sacc[s][r] * SC;
        xm = fmaxf(xm, xs[s][r]);
      }
    xm = fmaxf(xm, __shfl_xor(xm, 16, 64));
    xm = fmaxf(xm, __shfl_xor(xm, 32, 64));
    const float mn = fmaxf(mrun, xm);
    const float corr = __builtin_amdgcn_exp2f(mrun - mn);
    mrun = mn;
    float ps = 0.f;
#pragma unroll
    for (int s = 0; s < 4; ++s) {
      float p[4];
#pragma unroll
      for (int r = 0; r < 4; ++r) {
        p[r] = __builtin_amdgcn_exp2f(xs[s][r] - mn);
        ps += p[r];
      }
      *reinterpret_cast<s16x4*>(&Plds[w][fr][s * 16 + fg * 4]) =
          cvt4(p[0], p[1], p[2], p[3]);
    }
    ps += __shfl_xor(ps, 16, 64);
    ps += __shfl_xor(ps, 32, 64);
    lsum = lsum * corr + ps;
    __builtin_amdgcn_wave_barrier();
    s16x8 pa0 = *reinterpret_cast<const s16x8*>(&Plds[w][fr][fg * 8]);
    s16x8 pa1 = *reinterpret_cast<const s16x8*>(&Plds[w][fr][32 + fg * 8]);
#pragma unroll
    for (int c = 0; c < 4; ++c) {
      s16x8 vf0 = *reinterpret_cast<const s16x8*>(&Vls[g][c * 16 + fr][fg * 8]);
      s16x8 vf1 = *reinterpret_cast<const s16x8*>(&Vls[g][c * 16 + fr][32 + fg * 8]);
      fx4 h = hacc[c];
#pragma unroll
      for (int r = 0; r < 4; ++r) h[r] *= corr;
      h = mfma16(vf0, pa0, h);
      hacc[c] = mfma16(vf1, pa1, h);
    }
    __syncthreads();  // all waves done reading tile it
    if (it + 1 < KVQ / 64) {
      *reinterpret_cast<s16x8*>(&Kls[g][srow][sch])     = pk0;
      *reinterpret_cast<s16x8*>(&Kls[g][srow][sch + 8]) = pk1;
      *reinterpret_cast<s16x8*>(&Vls[g][srow][sch])     = pv0;
      *reinterpret_cast<s16x8*>(&Vls[g][srow][sch + 8]) = pv1;
    }
    __syncthreads();  // tile it+1 visible
  }
#pragma unroll
  for (int c = 0; c < 4; ++c)
    *reinterpret_cast<fx4*>(&HL[g][wl * 16 + fr][c * 16 + fg * 4]) = hacc[c];
  if (fg == 0) ML[g][wl * 16 + fr] = make_float2(mrun, lsum);
  __syncthreads();
  const int row = t >> 4, d0 = (t & 15) * 4;
  const float2 s0 = ML[0][row], s1 = ML[1][row], s2 = ML[2][row], s3 = ML[3][row];
  const float mm = fmaxf(fmaxf(s0.x, s1.x), fmaxf(s2.x, s3.x));
  const float w0 = __builtin_amdgcn_exp2f(s0.x - mm);
  const float w1 = __builtin_amdgcn_exp2f(s1.x - mm);
  const float w2 = __builtin_amdgcn_exp2f(s2.x - mm);
  const float w3 = __builtin_amdgcn_exp2f(s3.x - mm);
  const float inv = 1.0f / (s0.y * w0 + s1.y * w1 + s2.y * w2 + s3.y * w3);
  fx4 h0 = *reinterpret_cast<const fx4*>(&HL[0][row][d0]);
  fx4 h1 = *reinterpret_cast<const fx4*>(&HL[1][row][d0]);
  fx4 h2 = *reinterpret_cast<const fx4*>(&HL[2][row][d0]);
  fx4 h3 = *reinterpret_cast<const fx4*>(&HL[3][row][d0]);
  fx4 o;
#pragma unroll
  for (int r = 0; r < 4; ++r)
    o[r] = (h0[r] * w0 + h1[r] * w1 + h2[r] * w2 + h3[r] * w3) * inv;
  *reinterpret_cast<fx4*>(Out + ((size_t)b * LEN + q0 + row) * HD + d0) = o;
}

extern "C" void kernel_launch(void* const* d_in, const int* in_sizes, int n_in,
                              void* d_out, int out_size, void* d_ws, size_t ws_size,
                              hipStream_t stream) {
  const float* dec = (const float*)d_in[0];
  const float* enc = (const float*)d_in[1];
  const float* Wq  = (const float*)d_in[2];
  const float* bq  = (const float*)d_in[3];
  const float* Wk  = (const float*)d_in[4];
  const float* bk  = (const float*)d_in[5];
  const float* Wv  = (const float*)d_in[6];
  const float* bv  = (const float*)d_in[7];
  float* out = (float*)d_out;

  short* qws  = (short*)d_ws;                        // [16384,64] bf16
  short* kws  = qws + (size_t)M_TOT * HD;            // [16384,64] bf16
  short* vtws = kws + (size_t)M_TOT * HD;            // [16,64,1024] bf16
  short* wbuf = vtws + (size_t)NB * HD * LEN;        // [3][49152] bf16 weights

  convert_w_kernel<<<(3 * WELEM / 8) / 256, 256, 0, stream>>>(Wq, Wk, Wv, wbuf);
  proj_kernel<<<256, 256, 0, stream>>>(
      dec, enc, wbuf, bq, bk, bv, qws, kws, vtws);
  attn_kernel<<<NB * (LEN / 64), 1024, 0, stream>>>(qws, kws, vtws, out);
}